// Round 1
// baseline (54.327 us; speedup 1.0000x reference)
//
#include <hip/hip_runtime.h>

// out = 2 * circconv(d, b),  d = des@K, b = body@K   (circ matvec is commutative)
//
// Plan:
//   ws P[256][1024] f32 (1 MB): rows 0-127 = d, 128-255 = b. Zeroed each call.
//   k1: GEMM, M64 x N64 tiles, Ksplit=4 -> grid 256, atomicAdd partials into P.
//   k2: conv, 64 row-pairs x 4 j-quarters -> grid 256, atomicAdd 2*partial into out.

__global__ __launch_bounds__(256) void gemm_kernel(
    const float* __restrict__ des, const float* __restrict__ body,
    const float* __restrict__ kmat, float* __restrict__ P)
{
    // A staged transposed: At[kk][row] so the 8-row per-thread operand is a
    // contiguous float4 pair read (wave-broadcast, ~free). Pad 68 keeps float4
    // alignment (68*4 % 16 == 0) and limits write conflicts to 4-way.
    __shared__ float At[32][68];
    __shared__ float Kl[32][64];

    const int tid = threadIdx.x;
    const int bid = blockIdx.x;
    const int ks = bid & 3;            // K-split 0..3 (256 K each)
    const int nt = (bid >> 2) & 15;    // N-tile 0..15 (64 cols)
    const int mt = bid >> 6;           // M-tile 0..3  (64 virtual rows)
    const int m0 = mt * 64, n0 = nt * 64;
    const int cg = tid & 31;           // col group: cols 2cg, 2cg+1
    const int rg = tid >> 5;           // row group: rows 8rg .. 8rg+7

    const float* Asrc = (m0 < 128) ? des : body;   // block-uniform
    const int mb = m0 & 127;

    float acc[8][2];
    #pragma unroll
    for (int i = 0; i < 8; ++i) { acc[i][0] = 0.f; acc[i][1] = 0.f; }

    for (int kc = 0; kc < 8; ++kc) {
        const int kb = ks * 256 + kc * 32;
        // stage A-tile (64 rows x 32 k), transposed; coalesced 32-wide reads
        #pragma unroll
        for (int i = 0; i < 8; ++i) {
            int e = tid + i * 256;
            int r = e >> 5, kk = e & 31;
            At[kk][r] = Asrc[(mb + r) * 1024 + kb + kk];
        }
        // stage K-tile (32 k x 64 cols), row-major, coalesced 64-wide
        #pragma unroll
        for (int i = 0; i < 8; ++i) {
            int e = tid + i * 256;
            int kk = e >> 6, col = e & 63;
            Kl[kk][col] = kmat[(kb + kk) * 1024 + n0 + col];
        }
        __syncthreads();
        #pragma unroll
        for (int kk = 0; kk < 32; ++kk) {
            float4 a0 = *(const float4*)&At[kk][rg * 8];
            float4 a1 = *(const float4*)&At[kk][rg * 8 + 4];
            float2 kv = *(const float2*)&Kl[kk][cg * 2];
            acc[0][0] += a0.x * kv.x; acc[0][1] += a0.x * kv.y;
            acc[1][0] += a0.y * kv.x; acc[1][1] += a0.y * kv.y;
            acc[2][0] += a0.z * kv.x; acc[2][1] += a0.z * kv.y;
            acc[3][0] += a0.w * kv.x; acc[3][1] += a0.w * kv.y;
            acc[4][0] += a1.x * kv.x; acc[4][1] += a1.x * kv.y;
            acc[5][0] += a1.y * kv.x; acc[5][1] += a1.y * kv.y;
            acc[6][0] += a1.z * kv.x; acc[6][1] += a1.z * kv.y;
            acc[7][0] += a1.w * kv.x; acc[7][1] += a1.w * kv.y;
        }
        __syncthreads();
    }
    #pragma unroll
    for (int i = 0; i < 8; ++i) {
        int row = m0 + rg * 8 + i;
        atomicAdd(&P[row * 1024 + n0 + cg * 2],     acc[i][0]);
        atomicAdd(&P[row * 1024 + n0 + cg * 2 + 1], acc[i][1]);
    }
}

__global__ __launch_bounds__(256) void conv_kernel(
    const float* __restrict__ P, float* __restrict__ out)
{
    __shared__ float dl[2][1024];   // full d rows (window operand)
    __shared__ float bl[2][256];    // b j-quarter (broadcast operand)

    const int tid = threadIdx.x;
    const int bid = blockIdx.x;
    const int pair = bid >> 2, jq = bid & 3;
    const int m0 = pair * 2;

    // stage: d rows full (float4 coalesced), b quarters
    ((float4*)dl[0])[tid] = ((const float4*)(P + m0 * 1024))[tid];
    ((float4*)dl[1])[tid] = ((const float4*)(P + (m0 + 1) * 1024))[tid];
    if (tid < 64)
        ((float4*)bl[0])[tid] = ((const float4*)(P + (128 + m0) * 1024 + jq * 256))[tid];
    else if (tid < 128)
        ((float4*)bl[1])[tid - 64] = ((const float4*)(P + (129 + m0) * 1024 + jq * 256))[tid - 64];
    __syncthreads();

    const int half = tid >> 7, t = tid & 127;
    const float* d = dl[half];
    const float* b = bl[half];
    const int korig = t * 8;
    const int k0 = (korig - jq * 256) & 1023;   // fold j-offset into k base (stays %4==0)

    float acc[8];
    #pragma unroll
    for (int q = 0; q < 8; ++q) acc[q] = 0.f;

    // rolling window: A = d[k0-jc .. +3], Bv = d[k0-jc+4 .. +7] (all float4-aligned)
    float4 A  = *(const float4*)&d[k0];
    float4 Bv = *(const float4*)&d[(k0 + 4) & 1023];

    for (int jc = 0; jc < 256; jc += 4) {
        float4 bv = *(const float4*)&b[jc];                      // broadcast
        float4 Nv = *(const float4*)&d[(k0 - jc - 4) & 1023];    // new low window
        // s=0: idx base k0-jc
        acc[0] += bv.x * A.x;  acc[1] += bv.x * A.y;  acc[2] += bv.x * A.z;  acc[3] += bv.x * A.w;
        acc[4] += bv.x * Bv.x; acc[5] += bv.x * Bv.y; acc[6] += bv.x * Bv.z; acc[7] += bv.x * Bv.w;
        // s=1: idx base k0-jc-1
        acc[0] += bv.y * Nv.w; acc[1] += bv.y * A.x;  acc[2] += bv.y * A.y;  acc[3] += bv.y * A.z;
        acc[4] += bv.y * A.w;  acc[5] += bv.y * Bv.x; acc[6] += bv.y * Bv.y; acc[7] += bv.y * Bv.z;
        // s=2: idx base k0-jc-2
        acc[0] += bv.z * Nv.z; acc[1] += bv.z * Nv.w; acc[2] += bv.z * A.x;  acc[3] += bv.z * A.y;
        acc[4] += bv.z * A.z;  acc[5] += bv.z * A.w;  acc[6] += bv.z * Bv.x; acc[7] += bv.z * Bv.y;
        // s=3: idx base k0-jc-3
        acc[0] += bv.w * Nv.y; acc[1] += bv.w * Nv.z; acc[2] += bv.w * Nv.w; acc[3] += bv.w * A.x;
        acc[4] += bv.w * A.y;  acc[5] += bv.w * A.z;  acc[6] += bv.w * A.w;  acc[7] += bv.w * Bv.x;
        Bv = A; A = Nv;
    }

    float* o = out + (m0 + half) * 1024 + korig;
    #pragma unroll
    for (int q = 0; q < 8; ++q) atomicAdd(&o[q], 2.0f * acc[q]);
}

extern "C" void kernel_launch(void* const* d_in, const int* in_sizes, int n_in,
                              void* d_out, int out_size, void* d_ws, size_t ws_size,
                              hipStream_t stream) {
    const float* des  = (const float*)d_in[0];
    const float* body = (const float*)d_in[1];
    const float* kmat = (const float*)d_in[2];
    float* out = (float*)d_out;
    float* P   = (float*)d_ws;   // 256*1024 floats = 1 MB

    hipMemsetAsync(d_ws, 0, 256 * 1024 * sizeof(float), stream);
    hipMemsetAsync(d_out, 0, 128 * 1024 * sizeof(float), stream);
    gemm_kernel<<<256, 256, 0, stream>>>(des, body, kmat, P);
    conv_kernel<<<256, 256, 0, stream>>>(P, out);
}

// Round 2
// 36.509 us; speedup vs baseline: 1.4880x; 1.4880x over previous
//
#include <hip/hip_runtime.h>

// out = 2 * circconv(d, b),  d = des@K, b = body@K  (circ matvec is commutative)
//
// ws layout (no memsets, no atomics, fully deterministic):
//   Ppart [16][256][1024] f32 (16 MB) @ 0       split-K GEMM partials
//   P     [256][1024]     f32 ( 1 MB) @ 16 MB   reduced d (rows 0-127) / b (128-255)
//   Pconv [8][128][1024]  f32 ( 4 MB) @ 17 MB   conv j-octant partials
//
// k1 gemm:   512 blocks (2/CU), tile 128r x 64c, per-thread 8x4, K=64 per block
// k2 reduce1: P = sum_s Ppart[s]
// k3 conv:   512 blocks = 64 row-pairs x 8 j-octants, XOR-swizzled d window
// k4 reduce2: out = 2 * sum_jo Pconv[jo]

__global__ __launch_bounds__(256) void gemm_kernel(
    const float* __restrict__ des, const float* __restrict__ body,
    const float* __restrict__ kmat, float* __restrict__ Ppart)
{
    __shared__ float At[32][132];   // [k][row], stride 132 keeps b128 align, 2-ish-way write conflicts
    __shared__ float Kl[32][64];    // [k][col]

    const int tid = threadIdx.x;
    const int bid = blockIdx.x;
    const int ks = bid & 15;          // K-split 0..15 (64 K each)
    const int nt = (bid >> 4) & 15;   // N-tile (64 cols)
    const int mt = bid >> 8;          // 0 = des, 1 = body (128 rows)
    const int n0 = nt * 64;
    const int rg = tid >> 4;          // 16 row-groups of 8 rows
    const int cg = tid & 15;          // 16 col-groups of 4 cols

    const float* Asrc = mt ? body : des;

    float acc[8][4];
    #pragma unroll
    for (int i = 0; i < 8; ++i) {
        acc[i][0] = 0.f; acc[i][1] = 0.f; acc[i][2] = 0.f; acc[i][3] = 0.f;
    }

    for (int kc = 0; kc < 2; ++kc) {
        const int kb = ks * 64 + kc * 32;
        // stage A: 128 rows x 32 k, transposed into At[k][row]
        #pragma unroll
        for (int u = 0; u < 4; ++u) {
            int f = tid + u * 256;            // 1024 float4s
            int row = f >> 3, kq = f & 7;
            float4 a = *(const float4*)(Asrc + row * 1024 + kb + kq * 4);
            At[kq * 4 + 0][row] = a.x;
            At[kq * 4 + 1][row] = a.y;
            At[kq * 4 + 2][row] = a.z;
            At[kq * 4 + 3][row] = a.w;
        }
        // stage K: 32 k x 64 cols, row-major
        #pragma unroll
        for (int u = 0; u < 2; ++u) {
            int f = tid + u * 256;            // 512 float4s
            int kk = f >> 4, c4 = f & 15;
            *(float4*)&Kl[kk][c4 * 4] =
                *(const float4*)(kmat + (kb + kk) * 1024 + n0 + c4 * 4);
        }
        __syncthreads();
        #pragma unroll
        for (int kk = 0; kk < 32; ++kk) {
            float4 a0 = *(const float4*)&At[kk][rg * 8];
            float4 a1 = *(const float4*)&At[kk][rg * 8 + 4];
            float4 kv = *(const float4*)&Kl[kk][cg * 4];
            float ar[8] = {a0.x, a0.y, a0.z, a0.w, a1.x, a1.y, a1.z, a1.w};
            #pragma unroll
            for (int i = 0; i < 8; ++i) {
                acc[i][0] += ar[i] * kv.x; acc[i][1] += ar[i] * kv.y;
                acc[i][2] += ar[i] * kv.z; acc[i][3] += ar[i] * kv.w;
            }
        }
        __syncthreads();
    }
    float* dst = Ppart + ((size_t)ks * 256 + mt * 128) * 1024;
    #pragma unroll
    for (int i = 0; i < 8; ++i) {
        *(float4*)(dst + (rg * 8 + i) * 1024 + n0 + cg * 4) =
            make_float4(acc[i][0], acc[i][1], acc[i][2], acc[i][3]);
    }
}

__global__ __launch_bounds__(256) void reduce1_kernel(
    const float4* __restrict__ Pp, float4* __restrict__ P)
{
    int g = blockIdx.x * 256 + threadIdx.x;   // < 65536
    float4 s = Pp[g];
    #pragma unroll
    for (int k = 1; k < 16; ++k) {
        float4 v = Pp[k * 65536 + g];
        s.x += v.x; s.y += v.y; s.z += v.z; s.w += v.w;
    }
    P[g] = s;
}

__global__ __launch_bounds__(256) void conv_kernel(
    const float* __restrict__ P, float* __restrict__ Pc)
{
    __shared__ float dl[2][1024];   // swizzled: f4 slot i4 ^ ((i4>>3)&1)
    __shared__ float bl[2][128];

    const int tid = threadIdx.x;
    const int bid = blockIdx.x;
    const int jo = bid & 7, pair = bid >> 3;
    const int m0 = pair * 2, jbase = jo * 128;

    #pragma unroll
    for (int u = 0; u < 2; ++u) {
        int q = tid + u * 256;                 // 512 float4s (2 rows x 256)
        int row = q >> 8, i4 = q & 255;
        int sw = i4 ^ ((i4 >> 3) & 1);
        ((float4*)dl[row])[sw] = ((const float4*)(P + (m0 + row) * 1024))[i4];
    }
    if (tid < 64) {
        int row = tid >> 5, i4 = tid & 31;
        ((float4*)bl[row])[i4] =
            ((const float4*)(P + (128 + m0 + row) * 1024 + jbase))[i4];
    }
    __syncthreads();

    const int half = tid >> 7, t = tid & 127;
    const float* d = dl[half];
    const float* b = bl[half];
    const int k0 = (t * 8 - jbase) & 1023;

    float acc[8];
    #pragma unroll
    for (int q = 0; q < 8; ++q) acc[q] = 0.f;

    // swizzled float4 read of d at float index fidx (multiple of 4, pre-masked)
    #define RD(fidx) (((const float4*)d)[((fidx) >> 2) ^ ((((fidx) >> 2) >> 3) & 1)])

    float4 A  = RD(k0);
    float4 Bv = RD((k0 + 4) & 1023);

    for (int jc = 0; jc < 128; jc += 4) {
        float4 bv = *(const float4*)&b[jc];
        float4 Nv = RD((k0 - jc - 4) & 1023);
        // s=0: base k0-jc
        acc[0] += bv.x * A.x;  acc[1] += bv.x * A.y;  acc[2] += bv.x * A.z;  acc[3] += bv.x * A.w;
        acc[4] += bv.x * Bv.x; acc[5] += bv.x * Bv.y; acc[6] += bv.x * Bv.z; acc[7] += bv.x * Bv.w;
        // s=1
        acc[0] += bv.y * Nv.w; acc[1] += bv.y * A.x;  acc[2] += bv.y * A.y;  acc[3] += bv.y * A.z;
        acc[4] += bv.y * A.w;  acc[5] += bv.y * Bv.x; acc[6] += bv.y * Bv.y; acc[7] += bv.y * Bv.z;
        // s=2
        acc[0] += bv.z * Nv.z; acc[1] += bv.z * Nv.w; acc[2] += bv.z * A.x;  acc[3] += bv.z * A.y;
        acc[4] += bv.z * A.z;  acc[5] += bv.z * A.w;  acc[6] += bv.z * Bv.x; acc[7] += bv.z * Bv.y;
        // s=3
        acc[0] += bv.w * Nv.y; acc[1] += bv.w * Nv.z; acc[2] += bv.w * Nv.w; acc[3] += bv.w * A.x;
        acc[4] += bv.w * A.y;  acc[5] += bv.w * A.z;  acc[6] += bv.w * A.w;  acc[7] += bv.w * Bv.x;
        Bv = A; A = Nv;
    }
    #undef RD

    float4* o = (float4*)(Pc + ((size_t)jo * 128 + m0 + half) * 1024 + t * 8);
    o[0] = make_float4(acc[0], acc[1], acc[2], acc[3]);
    o[1] = make_float4(acc[4], acc[5], acc[6], acc[7]);
}

__global__ __launch_bounds__(256) void reduce2_kernel(
    const float4* __restrict__ Pc, float4* __restrict__ out)
{
    int g = blockIdx.x * 256 + threadIdx.x;   // < 32768
    float4 s = Pc[g];
    #pragma unroll
    for (int k = 1; k < 8; ++k) {
        float4 v = Pc[k * 32768 + g];
        s.x += v.x; s.y += v.y; s.z += v.z; s.w += v.w;
    }
    s.x *= 2.f; s.y *= 2.f; s.z *= 2.f; s.w *= 2.f;
    out[g] = s;
}

extern "C" void kernel_launch(void* const* d_in, const int* in_sizes, int n_in,
                              void* d_out, int out_size, void* d_ws, size_t ws_size,
                              hipStream_t stream) {
    const float* des  = (const float*)d_in[0];
    const float* body = (const float*)d_in[1];
    const float* kmat = (const float*)d_in[2];

    float* Pp = (float*)d_ws;                  // 16 MB
    float* P  = Pp + 16 * 256 * 1024;          //  1 MB
    float* Pc = P + 256 * 1024;                //  4 MB

    gemm_kernel<<<512, 256, 0, stream>>>(des, body, kmat, Pp);
    reduce1_kernel<<<256, 256, 0, stream>>>((const float4*)Pp, (float4*)P);
    conv_kernel<<<512, 256, 0, stream>>>(P, Pc);
    reduce2_kernel<<<128, 256, 0, stream>>>((const float4*)Pc, (float4*)d_out);
}

// Round 3
// 32.312 us; speedup vs baseline: 1.6813x; 1.1299x over previous
//
#include <hip/hip_runtime.h>

// out = 2 * circconv(d, b),  d = des@K, b = body@K   (circ matvec is commutative)
//
// Two kernels, no atomics, no memsets, deterministic:
//   k1 gemm: split-K=8, 64x64 tiles, grid 512 (2/CU) -> Pp[8][256][1024] (8 MB)
//            rows 0-127 = d-partials, 128-255 = b-partials
//   k2 conv: grid 256 = 128 rows x 2 k-halves. Stage d-row/b-row into LDS while
//            summing the 8 partials inline (fused reduce). Each thread: 2 even-
//            aligned k's via rolling float2 window. Direct store 2*acc to out.

__global__ __launch_bounds__(256) void gemm_kernel(
    const float* __restrict__ des, const float* __restrict__ body,
    const float* __restrict__ kmat, float* __restrict__ Pp)
{
    __shared__ float At[32][68];   // [k][row], 68*4=272B rows keep b128 align
    __shared__ float Kl[32][64];   // [k][col]

    const int tid = threadIdx.x;
    const int bid = blockIdx.x;
    const int ks = bid & 7;           // K-split 0..7 (128 K each)
    const int nt = (bid >> 3) & 15;   // N-tile (64 cols)
    const int mt = bid >> 7;          // 0..3 (64 virtual rows each)
    const int n0 = nt * 64;
    const int rg = tid >> 4;          // 16 row-groups of 4 rows
    const int cg = tid & 15;          // 16 col-groups of 4 cols

    const float* Asrc = (mt < 2) ? des : body;
    const int rbase = (mt & 1) * 64;

    float acc[4][4];
    #pragma unroll
    for (int i = 0; i < 4; ++i)
        #pragma unroll
        for (int j = 0; j < 4; ++j) acc[i][j] = 0.f;

    for (int kc = 0; kc < 4; ++kc) {
        const int kb = ks * 128 + kc * 32;
        // stage A: 64 rows x 32 k, transposed -> At[k][row]; 512 float4 loads
        #pragma unroll
        for (int u = 0; u < 2; ++u) {
            int f = tid + u * 256;
            int row = f >> 3, kq = f & 7;
            float4 a = *(const float4*)(Asrc + (rbase + row) * 1024 + kb + kq * 4);
            At[kq * 4 + 0][row] = a.x;
            At[kq * 4 + 1][row] = a.y;
            At[kq * 4 + 2][row] = a.z;
            At[kq * 4 + 3][row] = a.w;
        }
        // stage K: 32 k x 64 cols, row-major; 512 float4s
        #pragma unroll
        for (int u = 0; u < 2; ++u) {
            int f = tid + u * 256;
            int kk = f >> 4, c4 = f & 15;
            *(float4*)&Kl[kk][c4 * 4] =
                *(const float4*)(kmat + (kb + kk) * 1024 + n0 + c4 * 4);
        }
        __syncthreads();
        #pragma unroll
        for (int kk = 0; kk < 32; ++kk) {
            float4 a  = *(const float4*)&At[kk][rg * 4];
            float4 kv = *(const float4*)&Kl[kk][cg * 4];
            acc[0][0] += a.x * kv.x; acc[0][1] += a.x * kv.y; acc[0][2] += a.x * kv.z; acc[0][3] += a.x * kv.w;
            acc[1][0] += a.y * kv.x; acc[1][1] += a.y * kv.y; acc[1][2] += a.y * kv.z; acc[1][3] += a.y * kv.w;
            acc[2][0] += a.z * kv.x; acc[2][1] += a.z * kv.y; acc[2][2] += a.z * kv.z; acc[2][3] += a.z * kv.w;
            acc[3][0] += a.w * kv.x; acc[3][1] += a.w * kv.y; acc[3][2] += a.w * kv.z; acc[3][3] += a.w * kv.w;
        }
        __syncthreads();
    }
    float* dst = Pp + ((size_t)ks * 256 + mt * 64) * 1024;
    #pragma unroll
    for (int i = 0; i < 4; ++i) {
        *(float4*)(dst + (rg * 4 + i) * 1024 + n0 + cg * 4) =
            make_float4(acc[i][0], acc[i][1], acc[i][2], acc[i][3]);
    }
}

__global__ __launch_bounds__(256) void conv_kernel(
    const float* __restrict__ Pp, float* __restrict__ out)
{
    __shared__ float dl[1024];
    __shared__ float bl[1024];

    const int tid = threadIdx.x;
    const int bid = blockIdx.x;
    const int r = bid >> 1;        // row 0..127
    const int h = bid & 1;         // k-half

    // fused reduce1: sum 8 split-K partials while staging (float4, coalesced)
    {
        float4 sd = make_float4(0.f, 0.f, 0.f, 0.f);
        float4 sb = make_float4(0.f, 0.f, 0.f, 0.f);
        #pragma unroll
        for (int s = 0; s < 8; ++s) {
            float4 vd = ((const float4*)(Pp + ((size_t)s * 256 + r) * 1024))[tid];
            float4 vb = ((const float4*)(Pp + ((size_t)s * 256 + 128 + r) * 1024))[tid];
            sd.x += vd.x; sd.y += vd.y; sd.z += vd.z; sd.w += vd.w;
            sb.x += vb.x; sb.y += vb.y; sb.z += vb.z; sb.w += vb.w;
        }
        ((float4*)dl)[tid] = sd;
        ((float4*)bl)[tid] = sb;
    }
    __syncthreads();

    const int k0 = h * 512 + tid * 2;   // even

    // two acc sets per output k break the FMA dep chain at low occupancy
    float a0a = 0.f, a0b = 0.f, a1a = 0.f, a1b = 0.f;

    // window elements e[i] = d[(k0 - jc - 4 + i) & 1023], i=0..5 as 3 float2s;
    // W2 rolls from previous chunk's W0.
    float2 W2 = *(const float2*)&dl[k0];

    for (int jc = 0; jc < 1024; jc += 8) {
        float4 bv0 = *(const float4*)&bl[jc];          // broadcast
        float2 W0  = *(const float2*)&dl[(k0 - jc - 4) & 1023];
        float2 W1  = *(const float2*)&dl[(k0 - jc - 2) & 1023];
        // chunk A: j = jc..jc+3
        a0a += bv0.x * W2.x + bv0.y * W1.y + bv0.z * W1.x + bv0.w * W0.y;
        a1a += bv0.x * W2.y + bv0.y * W2.x + bv0.z * W1.y + bv0.w * W1.x;

        float4 bv1 = *(const float4*)&bl[jc + 4];
        float2 V0  = *(const float2*)&dl[(k0 - jc - 8) & 1023];
        float2 V1  = *(const float2*)&dl[(k0 - jc - 6) & 1023];
        // chunk B: j = jc+4..jc+7, window shifted by 4 (W0 plays the W2 role)
        a0b += bv1.x * W0.x + bv1.y * V1.y + bv1.z * V1.x + bv1.w * V0.y;
        a1b += bv1.x * W0.y + bv1.y * W0.x + bv1.z * V1.y + bv1.w * V1.x;

        W2 = V0;
    }

    float2 o = make_float2(2.f * (a0a + a0b), 2.f * (a1a + a1b));
    *(float2*)(out + r * 1024 + k0) = o;
}

extern "C" void kernel_launch(void* const* d_in, const int* in_sizes, int n_in,
                              void* d_out, int out_size, void* d_ws, size_t ws_size,
                              hipStream_t stream) {
    const float* des  = (const float*)d_in[0];
    const float* body = (const float*)d_in[1];
    const float* kmat = (const float*)d_in[2];
    float* Pp = (float*)d_ws;   // 8 * 256 * 1024 floats = 8 MB

    gemm_kernel<<<512, 256, 0, stream>>>(des, body, kmat, Pp);
    conv_kernel<<<256, 256, 0, stream>>>(Pp, (float*)d_out);
}

// Round 5
// 29.108 us; speedup vs baseline: 1.8664x; 1.1101x over previous
//
#include <hip/hip_runtime.h>

// out = 2 * circconv(d, b),  d = des@K, b = body@K  (circ matvec is commutative)
//
// k1 gemm: bf16 MFMA 16x16x32, tile 128x128, split-K 16 (K=64/block, single-shot:
//          stage -> 1 sync -> 16 MFMA/wave -> store). grid 256 x 512thr.
//          Partials Pp[16][256][1024] bf16 (8 MB) in ws.
// k2 conv: grid 256 = 128 rows x 2 k-halves, block 256. Stage d-row/b-row summing
//          16 bf16 partials inline; rolling float2-window conv (R3 core); 2k/thread.
//
// R5 fix: B staging covered only cols 0..63 of the 128-col tile (half of Bl
// uninitialized -> NaN). Now loops both column halves: 512thr x 16 elem = 8192.

using bf16x8 = __attribute__((ext_vector_type(8))) short;
using f32x4  = __attribute__((ext_vector_type(4))) float;

static __device__ __forceinline__ unsigned short f2bf(float x) {
    union { float f; unsigned u; } v; v.f = x;
    return (unsigned short)((v.u + 0x7FFFu + ((v.u >> 16) & 1u)) >> 16);
}
static __device__ __forceinline__ float bf2f(unsigned short h) {
    union { unsigned u; float f; } v; v.u = ((unsigned)h) << 16;
    return v.f;
}

// LDS fragment-linear layouts (16B units, unit index -> one lane's b128 read):
//   A[r][k]: unit = (rg*2 + ks32)*64 + kg*16 + rr   rg=r>>4, rr=r&15, ks32=k>>5, kg=(k>>3)&3
//   B[k][c]: unit = (cg*2 + ks32)*64 + kg*16 + cc   cg=c>>4, cc=c&15
// byte-within-unit = (k&7)*2.

__global__ __launch_bounds__(512) void gemm_kernel(
    const float* __restrict__ des, const float* __restrict__ body,
    const float* __restrict__ kmat, unsigned short* __restrict__ Pp)
{
    __shared__ short Al[8192];   // 16 KB
    __shared__ short Bl[8192];   // 16 KB

    const int tid = threadIdx.x;
    const int bid = blockIdx.x;
    const int nt = bid & 7;            // N-tile (128 cols)
    const int ks = (bid >> 3) & 15;    // K-split (64 k)
    const int mt = bid >> 7;           // 0 = des rows 0-127, 1 = body rows 128-255
    const int n0 = nt * 128;
    const int kb = ks * 64;
    const float* Asrc = mt ? body : des;

    // stage A: tasks (r in [0,128), kq in [0,16)); 4 per thread; coalesced
    #pragma unroll
    for (int it = 0; it < 4; ++it) {
        int task = tid + it * 512;
        int r = task >> 4, kq = task & 15;
        float4 F = *(const float4*)(Asrc + r * 1024 + kb + kq * 4);
        int k = kq * 4;
        int unit = (((r >> 4) * 2 + (k >> 5)) << 6) + (((k >> 3) & 3) << 4) + (r & 15);
        unsigned lo = (unsigned)f2bf(F.x) | ((unsigned)f2bf(F.y) << 16);
        unsigned hi = (unsigned)f2bf(F.z) | ((unsigned)f2bf(F.w) << 16);
        *(uint2*)&Al[unit * 8 + (k & 7)] = make_uint2(lo, hi);
    }
    // stage B: 64 k x 128 cols = 8192 elems; thread (ke2, cq) does both col halves
    {
        int ke2 = tid >> 4, cq = tid & 15;
        int k = ke2 * 2;
        #pragma unroll
        for (int half = 0; half < 2; ++half) {
            int cbase = half * 64 + cq * 4;
            float4 Fa = *(const float4*)(kmat + (size_t)(kb + k) * 1024 + n0 + cbase);
            float4 Fb = *(const float4*)(kmat + (size_t)(kb + k + 1) * 1024 + n0 + cbase);
            const float fa[4] = {Fa.x, Fa.y, Fa.z, Fa.w};
            const float fb[4] = {Fb.x, Fb.y, Fb.z, Fb.w};
            #pragma unroll
            for (int u = 0; u < 4; ++u) {
                int c = cbase + u;
                int unit = (((c >> 4) * 2 + (k >> 5)) << 6) + (((k >> 3) & 3) << 4) + (c & 15);
                *(unsigned*)&Bl[unit * 8 + (k & 7)] =
                    (unsigned)f2bf(fa[u]) | ((unsigned)f2bf(fb[u]) << 16);
            }
        }
    }
    __syncthreads();

    const int lane = tid & 63;
    const int wid = tid >> 6;       // 8 waves: 4 row-bands x 2 col-bands
    const int wr = wid & 3;         // rows wr*32 .. wr*32+31
    const int wc = wid >> 2;        // cols wc*64 .. wc*64+63

    f32x4 acc[2][4];
    #pragma unroll
    for (int q = 0; q < 2; ++q)
        #pragma unroll
        for (int g = 0; g < 4; ++g)
            acc[q][g] = (f32x4){0.f, 0.f, 0.f, 0.f};

    #pragma unroll
    for (int s = 0; s < 2; ++s) {
        bf16x8 a0 = *(const bf16x8*)&Al[((((2 * wr + 0) * 2 + s) << 6) + lane) * 8];
        bf16x8 a1 = *(const bf16x8*)&Al[((((2 * wr + 1) * 2 + s) << 6) + lane) * 8];
        #pragma unroll
        for (int g = 0; g < 4; ++g) {
            bf16x8 bfr = *(const bf16x8*)&Bl[((((4 * wc + g) * 2 + s) << 6) + lane) * 8];
            // swapped operands: computes (A.B)^T so lane's 4 regs = 4 consecutive cols
            acc[0][g] = __builtin_amdgcn_mfma_f32_16x16x32_bf16(bfr, a0, acc[0][g], 0, 0, 0);
            acc[1][g] = __builtin_amdgcn_mfma_f32_16x16x32_bf16(bfr, a1, acc[1][g], 0, 0, 0);
        }
    }

    const int m0 = mt * 128;
    unsigned short* dst = Pp + (size_t)ks * 262144;
    #pragma unroll
    for (int q = 0; q < 2; ++q) {
        int row = m0 + wr * 32 + q * 16 + (lane & 15);
        #pragma unroll
        for (int g = 0; g < 4; ++g) {
            int col = n0 + wc * 64 + g * 16 + ((lane >> 4) << 2);
            f32x4 v = acc[q][g];
            ushort4 o;
            o.x = f2bf(v[0]); o.y = f2bf(v[1]); o.z = f2bf(v[2]); o.w = f2bf(v[3]);
            *(ushort4*)(dst + (size_t)row * 1024 + col) = o;
        }
    }
}

__global__ __launch_bounds__(256) void conv_kernel(
    const unsigned short* __restrict__ Pp, float* __restrict__ out)
{
    __shared__ float dl[1024];
    __shared__ float bl[1024];

    const int tid = threadIdx.x;
    const int bid = blockIdx.x;
    const int r = bid >> 1;        // row 0..127
    const int h = bid & 1;         // k-half

    // fused reduce: sum 16 bf16 partials while staging; tid<128 -> d, else -> b
    {
        int isB = tid >> 7;
        int ch = tid & 127;        // 8-elem chunk
        const unsigned short* src = Pp + (size_t)((isB ? 128 : 0) + r) * 1024 + ch * 8;
        float s[8] = {0.f, 0.f, 0.f, 0.f, 0.f, 0.f, 0.f, 0.f};
        #pragma unroll
        for (int sp = 0; sp < 16; ++sp) {
            uint4 v = *(const uint4*)(src + (size_t)sp * 262144);
            unsigned w[4] = {v.x, v.y, v.z, v.w};
            #pragma unroll
            for (int u = 0; u < 4; ++u) {
                s[u * 2 + 0] += bf2f((unsigned short)(w[u] & 0xFFFFu));
                s[u * 2 + 1] += bf2f((unsigned short)(w[u] >> 16));
            }
        }
        float* dstl = (isB ? bl : dl) + ch * 8;
        #pragma unroll
        for (int u = 0; u < 8; ++u) dstl[u] = s[u];
    }
    __syncthreads();

    const int k0 = h * 512 + tid * 2;   // even

    float a0a = 0.f, a0b = 0.f, a1a = 0.f, a1b = 0.f;
    float2 W2 = *(const float2*)&dl[k0];

    for (int jc = 0; jc < 1024; jc += 8) {
        float4 bv0 = *(const float4*)&bl[jc];
        float2 W0  = *(const float2*)&dl[(k0 - jc - 4) & 1023];
        float2 W1  = *(const float2*)&dl[(k0 - jc - 2) & 1023];
        a0a += bv0.x * W2.x + bv0.y * W1.y + bv0.z * W1.x + bv0.w * W0.y;
        a1a += bv0.x * W2.y + bv0.y * W2.x + bv0.z * W1.y + bv0.w * W1.x;

        float4 bv1 = *(const float4*)&bl[jc + 4];
        float2 V0  = *(const float2*)&dl[(k0 - jc - 8) & 1023];
        float2 V1  = *(const float2*)&dl[(k0 - jc - 6) & 1023];
        a0b += bv1.x * W0.x + bv1.y * V1.y + bv1.z * V1.x + bv1.w * V0.y;
        a1b += bv1.x * W0.y + bv1.y * W0.x + bv1.z * V1.y + bv1.w * V1.x;

        W2 = V0;
    }

    *(float2*)(out + r * 1024 + k0) =
        make_float2(2.f * (a0a + a0b), 2.f * (a1a + a1b));
}

extern "C" void kernel_launch(void* const* d_in, const int* in_sizes, int n_in,
                              void* d_out, int out_size, void* d_ws, size_t ws_size,
                              hipStream_t stream) {
    const float* des  = (const float*)d_in[0];
    const float* body = (const float*)d_in[1];
    const float* kmat = (const float*)d_in[2];
    unsigned short* Pp = (unsigned short*)d_ws;   // 16*256*1024 bf16 = 8 MB

    gemm_kernel<<<256, 512, 0, stream>>>(des, body, kmat, Pp);
    conv_kernel<<<256, 256, 0, stream>>>(Pp, (float*)d_out);
}